// Round 4
// baseline (224.011 us; speedup 1.0000x reference)
//
#include <hip/hip_runtime.h>

#define BTOT 1048576
#define D 17
#define H 8
#define OUT 6
#define E 4
#define G1 64
#define G2 32
#define CHUNKS 4
#define XSTR 20   // sxp row stride (fp32): 17 data + 3 zero pad; 80B rows, 16B aligned

typedef float f32x4 __attribute__((ext_vector_type(4)));
typedef float f32x2 __attribute__((ext_vector_type(2)));
typedef short s16x8 __attribute__((ext_vector_type(8)));
typedef unsigned int uint;
typedef unsigned short ushort_t;

union U4S8 { uint u[4]; s16x8 s; };

// round fp32 bits to bf16 (RNE), return as fp32 bit pattern (low 16 zeroed)
__device__ __forceinline__ uint bfr(uint u) {
    return (u + 0x7fffu + ((u >> 16) & 1u)) & 0xffff0000u;
}

// scalar 3-way bf16 split: v ~= h + m + l (bf16 bit patterns, low 16 bits)
__device__ __forceinline__ void split1(float v, uint &h, uint &m, uint &l) {
    uint hb = bfr(__float_as_uint(v));
    float r1 = v - __uint_as_float(hb);
    uint mb = bfr(__float_as_uint(r1));
    float r2 = r1 - __uint_as_float(mb);
    uint lb = bfr(__float_as_uint(r2));
    h = hb >> 16; m = mb >> 16; l = lb >> 16;
}

// split a pair (a,b) -> packed bf16x2 words (a in low, b in high)
__device__ __forceinline__ void split_pair(float a, float b, uint &hp, uint &mp, uint &lp) {
    uint ha = bfr(__float_as_uint(a));
    uint hb = bfr(__float_as_uint(b));
    hp = (ha >> 16) | hb;
    float ra = a - __uint_as_float(ha);
    float rb = b - __uint_as_float(hb);
    uint ma = bfr(__float_as_uint(ra));
    uint mb = bfr(__float_as_uint(rb));
    mp = (ma >> 16) | mb;
    float sa = ra - __uint_as_float(ma);
    float sb = rb - __uint_as_float(mb);
    lp = (bfr(__float_as_uint(sa)) >> 16) | bfr(__float_as_uint(sb));
}

// 8 fp32 (A-fragment k-slice, ascending k) -> 3 bf16x8 MFMA A-frags
__device__ __forceinline__ void split8(f32x4 va, f32x4 vb, s16x8 &fh, s16x8 &fm, s16x8 &fl) {
    U4S8 Hh, Mm, Ll;
    split_pair(va.x, va.y, Hh.u[0], Mm.u[0], Ll.u[0]);
    split_pair(va.z, va.w, Hh.u[1], Mm.u[1], Ll.u[1]);
    split_pair(vb.x, vb.y, Hh.u[2], Mm.u[2], Ll.u[2]);
    split_pair(vb.z, vb.w, Hh.u[3], Mm.u[3], Ll.u[3]);
    fh = Hh.s; fm = Mm.s; fl = Ll.s;
}

// 6-term fp32-accurate bf16x3 MFMA: D += (ah+am+al)*(bh+bm+bl), dropping O(2^-27) terms
#define MM6(dacc, ah, am, al, bh, bm, bl)                                        \
    dacc = __builtin_amdgcn_mfma_f32_16x16x32_bf16(al, bh, dacc, 0, 0, 0);       \
    dacc = __builtin_amdgcn_mfma_f32_16x16x32_bf16(am, bm, dacc, 0, 0, 0);       \
    dacc = __builtin_amdgcn_mfma_f32_16x16x32_bf16(ah, bl, dacc, 0, 0, 0);       \
    dacc = __builtin_amdgcn_mfma_f32_16x16x32_bf16(am, bh, dacc, 0, 0, 0);       \
    dacc = __builtin_amdgcn_mfma_f32_16x16x32_bf16(ah, bm, dacc, 0, 0, 0);       \
    dacc = __builtin_amdgcn_mfma_f32_16x16x32_bf16(ah, bh, dacc, 0, 0, 0);

#define WSTR 296  // expert-weight LDS stride (dwords): blocks start on bank groups {0,8,16,24}

__global__ __launch_bounds__(256, 2) void hybrid_ruc_kernel(
    const float* __restrict__ x,
    const float* __restrict__ eW1, const float* __restrict__ eb1,
    const float* __restrict__ eW2, const float* __restrict__ eb2,
    const float* __restrict__ eW3, const float* __restrict__ eb3,
    const float* __restrict__ gW1, const float* __restrict__ gb1,
    const float* __restrict__ gW2, const float* __restrict__ gb2,
    const float* __restrict__ gW3, const float* __restrict__ gb3,
    float* __restrict__ out)
{
    // ---- LDS: 20480 + 9216 + 13824 + 768 + 16384 + 4736 = 65408 B ----
    __shared__ __align__(16) float    sxp[256 * XSTR];   // x fp32, k>=17 zeroed
    __shared__ __align__(16) ushort_t sW1[3][64 * 24];   // W1^T [n][k<24] bf16 h/m/l (k 17..23 = 0)
    __shared__ __align__(16) ushort_t sW2[3][32 * 72];   // W2^T [n][k<64] bf16, row stride 72
    __shared__ __align__(16) ushort_t sW3[3][4 * 32];    // W3^T [n][k<32] bf16
    __shared__ __align__(16) float    sscr[4][1024];     // per-wave scratch (h1/h2/logits)
    __shared__ __align__(16) float    swl[E * WSTR];     // expert weights (R1 layout)

    const int tid = threadIdx.x;
    const int wv  = tid >> 6;
    const int ln  = tid & 63;
    const int g   = ln >> 4;   // k-block group for MFMA fragments
    const int nn  = ln & 15;   // row (A) / col (B,D) within 16-tile
    float* scr = sscr[wv];

    // ======== one-time staging ========
    // gating W1^T: [64 n][24 k], zero-padded k in [17,24)
    for (int t = tid; t < 64 * 24; t += 256) {
        int n = t / 24, k = t % 24;
        float v = (k < D) ? gW1[k * G1 + n] : 0.0f;
        uint h, m, l; split1(v, h, m, l);
        sW1[0][t] = (ushort_t)h; sW1[1][t] = (ushort_t)m; sW1[2][t] = (ushort_t)l;
    }
    // gating W2^T: [32 n][64 k] at stride 72 (pads never read)
    for (int t = tid; t < 32 * 64; t += 256) {
        int n = t >> 6, k = t & 63;
        uint h, m, l; split1(gW2[k * G2 + n], h, m, l);
        int a = n * 72 + k;
        sW2[0][a] = (ushort_t)h; sW2[1][a] = (ushort_t)m; sW2[2][a] = (ushort_t)l;
    }
    // gating W3^T: [4 n][32 k]
    if (tid < 4 * 32) {
        int n = tid >> 5, k = tid & 31;
        uint h, m, l; split1(gW3[k * E + n], h, m, l);
        int a = n * 32 + k;
        sW3[0][a] = (ushort_t)h; sW3[1][a] = (ushort_t)m; sW3[2][a] = (ushort_t)l;
    }
    // expert weights (R1 bank-group layout)
    for (int t = tid; t < E * D * H; t += 256) {          // eW1: 544
        swl[(t / 136) * WSTR + (t % 136)] = eW1[t];
    }
    if (tid < E * H * H) {                                 // eW2: 256
        swl[(tid / 64) * WSTR + 144 + (tid % 64)] = eW2[tid];
    }
    if (tid < E * H * OUT) {                               // eW3: 192, rows padded to 8
        int e = tid / 48, r = tid % 48, k = r / 6, o = r % 6;
        swl[e * WSTR + 216 + k * 8 + o] = eW3[tid];
    }
    if (tid < E * H) swl[(tid / 8) * WSTR + 136 + (tid % 8)] = eb1[tid];
    if (tid < E * H) swl[(tid / 8) * WSTR + 208 + (tid % 8)] = eb2[tid];
    if (tid < E * OUT) swl[(tid / 6) * WSTR + 280 + (tid % 6)] = eb3[tid];
    __syncthreads();

    // ======== hoist gating biases + B-fragments into registers ========
    float cb1[4], cb2[2], cb3;
    #pragma unroll
    for (int ct = 0; ct < 4; ++ct) cb1[ct] = gb1[ct * 16 + nn];
    cb2[0] = gb2[nn]; cb2[1] = gb2[16 + nn];
    cb3 = (nn < 4) ? gb3[nn] : 0.0f;

    const s16x8 z8 = {0, 0, 0, 0, 0, 0, 0, 0};
    s16x8 B1f[3][4];                 // [kind][col-tile]; k = g*8..g*8+7 (g==3 all-zero)
    #pragma unroll
    for (int kd = 0; kd < 3; ++kd)
        #pragma unroll
        for (int ct = 0; ct < 4; ++ct)
            B1f[kd][ct] = (g <= 2) ? *(const s16x8*)(&sW1[kd][(ct * 16 + nn) * 24 + g * 8]) : z8;
    s16x8 B2f[3][2][2];              // [kind][col-tile][k-tile]; k = kt*32 + g*8
    #pragma unroll
    for (int kd = 0; kd < 3; ++kd)
        #pragma unroll
        for (int ct = 0; ct < 2; ++ct)
            #pragma unroll
            for (int kt = 0; kt < 2; ++kt)
                B2f[kd][ct][kt] = *(const s16x8*)(&sW2[kd][(ct * 16 + nn) * 72 + kt * 32 + g * 8]);
    s16x8 B3f[3];
    #pragma unroll
    for (int kd = 0; kd < 3; ++kd)
        B3f[kd] = (nn < 4) ? *(const s16x8*)(&sW3[kd][nn * 32 + g * 8]) : z8;

    // ======== chunk loop: 4 chunks of 256 samples ========
    #pragma unroll 1
    for (int c = 0; c < CHUNKS; ++c) {
        if (c) __syncthreads();                       // prev chunk's sxp readers done
        const long long cbase = ((long long)blockIdx.x * CHUNKS + c) * 256;

        // stage x chunk: fp32 [256][20], k in [17,20) zeroed
        for (int t = tid; t < 256 * D; t += 256) {
            int s = t / D, k = t % D;
            sxp[s * XSTR + k] = x[cbase * D + t];
        }
        {
            int s = tid; // 256 rows, 3 pad elems each
            sxp[s * XSTR + 17] = 0.0f;
            sxp[s * XSTR + 18] = 0.0f;
            sxp[s * XSTR + 19] = 0.0f;
        }
        __syncthreads();

        // ---- gating via MFMA (per-wave: 4 row-tiles of 16 samples) ----
        f32x4 Lg[4];
        const f32x4 z4 = {0.0f, 0.0f, 0.0f, 0.0f};
        #pragma unroll
        for (int rt = 0; rt < 4; ++rt) {
            const int srow = wv * 64 + rt * 16 + nn;
            // A1 frags from sxp (k = g*8..; g==2 upper half & g==3 are zero)
            f32x4 xa = (g <= 2) ? *(const f32x4*)(&sxp[srow * XSTR + g * 8]) : z4;
            f32x4 xb = (g <= 1) ? *(const f32x4*)(&sxp[srow * XSTR + g * 8 + 4]) : z4;
            s16x8 a1h, a1m, a1l; split8(xa, xb, a1h, a1m, a1l);

            // L1: 17->64, 4 col-tiles
            #pragma unroll
            for (int ct = 0; ct < 4; ++ct) {
                f32x4 d = {cb1[ct], cb1[ct], cb1[ct], cb1[ct]};
                MM6(d, a1h, a1m, a1l, B1f[0][ct], B1f[1][ct], B1f[2][ct]);
                // relu + swizzled h1 write: [16 s][64 n], 16B-block XOR (s&15)
                #pragma unroll
                for (int r = 0; r < 4; ++r) {
                    float hv = fmaxf(d[r], 0.0f);
                    int s = g * 4 + r, n = ct * 16 + nn;
                    scr[s * 64 + (((n >> 2) ^ (s & 15)) << 2) + (n & 3)] = hv;
                }
            }

            // A2 frags from h1 (k = kt*32 + g*8 ..)
            s16x8 a2h[2], a2m[2], a2l[2];
            #pragma unroll
            for (int kt = 0; kt < 2; ++kt) {
                int kb0 = kt * 8 + g * 2;
                f32x4 va = *(const f32x4*)(&scr[nn * 64 + ((kb0 ^ (nn & 15)) << 2)]);
                f32x4 vb = *(const f32x4*)(&scr[nn * 64 + (((kb0 + 1) ^ (nn & 15)) << 2)]);
                split8(va, vb, a2h[kt], a2m[kt], a2l[kt]);
            }

            // L2: 64->32, 2 col-tiles x 2 k-tiles
            #pragma unroll
            for (int ct = 0; ct < 2; ++ct) {
                f32x4 d = {cb2[ct], cb2[ct], cb2[ct], cb2[ct]};
                #pragma unroll
                for (int kt = 0; kt < 2; ++kt) {
                    MM6(d, a2h[kt], a2m[kt], a2l[kt], B2f[0][ct][kt], B2f[1][ct][kt], B2f[2][ct][kt]);
                }
                // relu + swizzled h2 write: [16 s][32 n], block XOR (s&7)
                #pragma unroll
                for (int r = 0; r < 4; ++r) {
                    float hv = fmaxf(d[r], 0.0f);
                    int s = g * 4 + r, n = ct * 16 + nn;
                    scr[s * 32 + (((n >> 2) ^ (s & 7)) << 2) + (n & 3)] = hv;
                }
            }

            // A3 frags from h2 (K=32)
            s16x8 a3h, a3m, a3l;
            {
                f32x4 va = *(const f32x4*)(&scr[nn * 32 + (((2 * g) ^ (nn & 7)) << 2)]);
                f32x4 vb = *(const f32x4*)(&scr[nn * 32 + (((2 * g + 1) ^ (nn & 7)) << 2)]);
                split8(va, vb, a3h, a3m, a3l);
            }
            // L3: 32->4 (cols n>=4 are zero-frag, never read)
            f32x4 d3 = {cb3, cb3, cb3, cb3};
            MM6(d3, a3h, a3m, a3l, B3f[0], B3f[1], B3f[2]);
            Lg[rt] = d3;
        }

        // ---- redistribute logits: D-layout -> one sample per lane ----
        if (nn < 4) {
            #pragma unroll
            for (int rt = 0; rt < 4; ++rt)
                #pragma unroll
                for (int r = 0; r < 4; ++r)
                    scr[(rt * 16 + g * 4 + r) * 4 + nn] = Lg[rt][r];
        }
        f32x4 lgv = *(const f32x4*)(&scr[ln * 4]);

        // ---- argmax, first-max-wins ----
        int sel = 0; float best = lgv.x;
        if (lgv.y > best) { best = lgv.y; sel = 1; }
        if (lgv.z > best) { best = lgv.z; sel = 2; }
        if (lgv.w > best) { best = lgv.w; sel = 3; }

        // ---- selected expert only (R1 path), x row from sxp ----
        const float* xrow = &sxp[tid * XSTR];
        float xr[D];
        {
            f32x4 x0 = *(const f32x4*)(xrow);
            f32x4 x1 = *(const f32x4*)(xrow + 4);
            f32x4 x2 = *(const f32x4*)(xrow + 8);
            f32x4 x3 = *(const f32x4*)(xrow + 12);
            xr[0]=x0.x; xr[1]=x0.y; xr[2]=x0.z; xr[3]=x0.w;
            xr[4]=x1.x; xr[5]=x1.y; xr[6]=x1.z; xr[7]=x1.w;
            xr[8]=x2.x; xr[9]=x2.y; xr[10]=x2.z; xr[11]=x2.w;
            xr[12]=x3.x; xr[13]=x3.y; xr[14]=x3.z; xr[15]=x3.w;
            xr[16]=xrow[16];
        }
        const float* wl = &swl[sel * WSTR];

        float t1[H];
        {
            f32x4 ba = *(const f32x4*)(wl + 136);
            f32x4 bb = *(const f32x4*)(wl + 140);
            t1[0]=ba.x; t1[1]=ba.y; t1[2]=ba.z; t1[3]=ba.w;
            t1[4]=bb.x; t1[5]=bb.y; t1[6]=bb.z; t1[7]=bb.w;
        }
        #pragma unroll
        for (int i = 0; i < D; ++i) {
            const float xi = xr[i];
            f32x4 wa = *(const f32x4*)(wl + i * 8);
            f32x4 wb = *(const f32x4*)(wl + i * 8 + 4);
            t1[0] = __builtin_fmaf(xi, wa.x, t1[0]);
            t1[1] = __builtin_fmaf(xi, wa.y, t1[1]);
            t1[2] = __builtin_fmaf(xi, wa.z, t1[2]);
            t1[3] = __builtin_fmaf(xi, wa.w, t1[3]);
            t1[4] = __builtin_fmaf(xi, wb.x, t1[4]);
            t1[5] = __builtin_fmaf(xi, wb.y, t1[5]);
            t1[6] = __builtin_fmaf(xi, wb.z, t1[6]);
            t1[7] = __builtin_fmaf(xi, wb.w, t1[7]);
        }
        float t2[H];
        {
            f32x4 ba = *(const f32x4*)(wl + 208);
            f32x4 bb = *(const f32x4*)(wl + 212);
            t2[0]=ba.x; t2[1]=ba.y; t2[2]=ba.z; t2[3]=ba.w;
            t2[4]=bb.x; t2[5]=bb.y; t2[6]=bb.z; t2[7]=bb.w;
        }
        #pragma unroll
        for (int k = 0; k < H; ++k) {
            const float tv = fmaxf(t1[k], 0.0f);
            f32x4 wa = *(const f32x4*)(wl + 144 + k * 8);
            f32x4 wb = *(const f32x4*)(wl + 144 + k * 8 + 4);
            t2[0] = __builtin_fmaf(tv, wa.x, t2[0]);
            t2[1] = __builtin_fmaf(tv, wa.y, t2[1]);
            t2[2] = __builtin_fmaf(tv, wa.z, t2[2]);
            t2[3] = __builtin_fmaf(tv, wa.w, t2[3]);
            t2[4] = __builtin_fmaf(tv, wb.x, t2[4]);
            t2[5] = __builtin_fmaf(tv, wb.y, t2[5]);
            t2[6] = __builtin_fmaf(tv, wb.z, t2[6]);
            t2[7] = __builtin_fmaf(tv, wb.w, t2[7]);
        }
        float pred[OUT];
        {
            f32x4 ba = *(const f32x4*)(wl + 280);
            pred[0]=ba.x; pred[1]=ba.y; pred[2]=ba.z; pred[3]=ba.w;
            pred[4]=wl[284]; pred[5]=wl[285];
        }
        #pragma unroll
        for (int k = 0; k < H; ++k) {
            const float tv = fmaxf(t2[k], 0.0f);
            f32x4 wa = *(const f32x4*)(wl + 216 + k * 8);
            f32x2 wb = *(const f32x2*)(wl + 216 + k * 8 + 4);
            pred[0] = __builtin_fmaf(tv, wa.x, pred[0]);
            pred[1] = __builtin_fmaf(tv, wa.y, pred[1]);
            pred[2] = __builtin_fmaf(tv, wa.z, pred[2]);
            pred[3] = __builtin_fmaf(tv, wa.w, pred[3]);
            pred[4] = __builtin_fmaf(tv, wb.x, pred[4]);
            pred[5] = __builtin_fmaf(tv, wb.y, pred[5]);
        }

        // ---- stores ----
        const long long b = cbase + tid;
        f32x2 p0 = {pred[0], pred[1]};
        f32x2 p1 = {pred[2], pred[3]};
        f32x2 p2 = {pred[4], pred[5]};
        *(f32x2*)(out + b * 6)     = p0;
        *(f32x2*)(out + b * 6 + 2) = p1;
        *(f32x2*)(out + b * 6 + 4) = p2;
        float* lout = out + (long long)BTOT * OUT;
        *(f32x4*)(lout + b * 4) = lgv;
    }
}

extern "C" void kernel_launch(void* const* d_in, const int* in_sizes, int n_in,
                              void* d_out, int out_size, void* d_ws, size_t ws_size,
                              hipStream_t stream) {
    const float* x   = (const float*)d_in[0];
    const float* eW1 = (const float*)d_in[1];
    const float* eb1 = (const float*)d_in[2];
    const float* eW2 = (const float*)d_in[3];
    const float* eb2 = (const float*)d_in[4];
    const float* eW3 = (const float*)d_in[5];
    const float* eb3 = (const float*)d_in[6];
    const float* gW1 = (const float*)d_in[7];
    const float* gb1 = (const float*)d_in[8];
    const float* gW2 = (const float*)d_in[9];
    const float* gb2 = (const float*)d_in[10];
    const float* gW3 = (const float*)d_in[11];
    const float* gb3 = (const float*)d_in[12];
    float* out = (float*)d_out;

    dim3 grid(BTOT / (256 * CHUNKS)), block(256);
    hipLaunchKernelGGL(hybrid_ruc_kernel, grid, block, 0, stream,
                       x, eW1, eb1, eW2, eb2, eW3, eb3,
                       gW1, gb1, gW2, gb2, gW3, gb3, out);
}